// Round 6
// baseline (115.080 us; speedup 1.0000x reference)
//
#include <hip/hip_runtime.h>
#include <math.h>

#define N 4096
#define D 128
#define TS 128                     // output tile per 256-thread block
#define NT (N / TS)                // 32 tile rows
#define NBLK (NT * (NT + 1) / 2)   // 528 lower-triangle tile pairs
#define NG (N / 16)                // 256 row groups of 16

typedef __attribute__((ext_vector_type(8))) short short8;  // 8 x bf16
typedef __attribute__((ext_vector_type(4))) float f32x4;

union frag_u { short8 v; unsigned int u[4]; };

__device__ __forceinline__ unsigned int pack_bf16x2(float a, float b) {
    unsigned int ua = __float_as_uint(a), ub = __float_as_uint(b);
    ua = (ua + 0x7FFFu + ((ua >> 16) & 1u)) >> 16;
    ub = (ub + 0x7FFFu + ((ub >> 16) & 1u)) >> 16;
    return ua | (ub << 16);
}

// Kernel 1: repack O into MFMA-fragment order + compute s[i]=sqrt(1+||o_i||^2).
// Unchanged: per-element values must stay bit-identical across rounds.
__global__ __launch_bounds__(256)
void prep_kernel(const float* __restrict__ O,
                 short8* __restrict__ Ofrag,
                 float* __restrict__ s) {
    __shared__ float psum[16][17];
    const int g    = blockIdx.x;          // 16-row group
    const int tid  = threadIdx.x;
    const int kk   = tid >> 6;            // 0..3 (wave = K-chunk)
    const int lane = tid & 63;
    const int r16  = lane & 15;
    const int qd   = lane >> 4;           // 0..3
    const float* src = O + (size_t)(g * 16 + r16) * D + kk * 32 + qd * 8;
    const float4 v0 = *(const float4*)(src);
    const float4 v1 = *(const float4*)(src + 4);
    frag_u f;
    f.u[0] = pack_bf16x2(v0.x, v0.y);
    f.u[1] = pack_bf16x2(v0.z, v0.w);
    f.u[2] = pack_bf16x2(v1.x, v1.y);
    f.u[3] = pack_bf16x2(v1.z, v1.w);
    Ofrag[(g * 4 + kk) * 64 + lane] = f.v;
    psum[kk * 4 + qd][r16] = v0.x * v0.x + v0.y * v0.y + v0.z * v0.z + v0.w * v0.w
                           + v1.x * v1.x + v1.y * v1.y + v1.z * v1.z + v1.w * v1.w;
    __syncthreads();
    if (tid < 16) {
        float acc = 1.0f;
        #pragma unroll
        for (int x = 0; x < 16; x++) acc += psum[x][tid];
        s[g * 16 + tid] = sqrtf(acc);
    }
}

__device__ __forceinline__ float acosh_dist(float B) {
    // clamp branch |B-1|<1e-6 -> 0 (inert here: B >= ~100 for this data)
    if (fabsf(B - 1.0f) < 1e-6f) return 0.0f;
    const float Bc = fmaxf(B, 1.0f);
    return __log2f(Bc + sqrtf(fmaf(Bc, Bc, -1.0f))) * 0.6931471805599453f;
}

// Async 16B global->LDS (no VGPR round-trip). LDS dest is wave-uniform base;
// HW adds lane*16 bytes.
__device__ __forceinline__ void gload_lds16(const float* g, float* l) {
    __builtin_amdgcn_global_load_lds(
        (const __attribute__((address_space(1))) unsigned int*)g,
        (__attribute__((address_space(3))) unsigned int*)l,
        16, 0, 0);
}

__device__ __forceinline__ void tile_ij(int t, int& ti_, int& tj_) {
    int x = (int)((sqrtf(8.0f * (float)t + 1.0f) - 1.0f) * 0.5f);
    while ((x + 1) * (x + 2) / 2 <= t) x++;
    while (x * (x + 1) / 2 > t) x--;
    ti_ = x;
    tj_ = t - x * (x + 1) / 2;
}

// Kernel 2: 528 blocks, one 128x128 tile each (4x the work per block of the
// old 64x64 version -> per-block fixed costs amortized 4x, frag L2 traffic
// halved). Each wave owns a 32x128 strip: acc[2][8] (2 row-groups x 8
// col-groups), K=128 in 4 chunks. B-frags processed in TWO HALVES with a
// sched_barrier between them so at most {acc 64 + A 32 + Bhalf 64 + misc}
// ~190 VGPR are live (R2/R4 spill trap excluded; cap 256 at (256,2)).
// tgt staged by 16 DMA instr/wave into linear T; wave w reads only the rows
// its own DMAs wrote -> per-wave vmcnt, ZERO barriers.
// Per-element math identical to prior rounds; accumulation upgraded to f64.
__global__ __launch_bounds__(256, 2)
void tile_loss_kernel(const short8* __restrict__ Fr,
                      const float* __restrict__ s,
                      const float* __restrict__ tgt,
                      float* __restrict__ wpart) {
    __shared__ float T[TS][TS];     // 64 KB, linear (DMA dest)

    const int tid  = threadIdx.x;
    const int wave = tid >> 6;
    const int lane = tid & 63;
    const int quad = lane >> 4;
    const int l16  = lane & 15;

    int ti, tj;
    tile_ij(blockIdx.x, ti, tj);
    const int ib0 = ti * TS;
    const int jb  = tj * TS;

    // ---- 1) DMA this wave's 32 tgt rows -> T[wave*32 .. +32). Each instr
    // writes 1 KB = 2 rows: lane l supplies row +(l>>5), cols (l&31)*4..+3.
    {
        const float* g = tgt + (size_t)(ib0 + wave * 32 + (lane >> 5)) * N
                       + jb + (lane & 31) * 4;
        #pragma unroll
        for (int q = 0; q < 16; q++)
            gload_lds16(g + (size_t)(2 * q) * N, &T[wave * 32 + 2 * q][0]);
    }
    __builtin_amdgcn_sched_barrier(0);

    // ---- 2) A-frags (2 row-groups x 4 K-chunks) + s values.
    short8 a[2][4];
    #pragma unroll
    for (int rg = 0; rg < 2; rg++)
        #pragma unroll
        for (int k = 0; k < 4; k++)
            a[rg][k] = Fr[((ti * 8 + wave * 2 + rg) * 4 + k) * 64 + lane];

    const int rbase = wave * 32 + quad * 4;
    float si[2][4], sj[8];
    #pragma unroll
    for (int rg = 0; rg < 2; rg++)
        #pragma unroll
        for (int r = 0; r < 4; r++)
            si[rg][r] = s[ib0 + rbase + rg * 16 + r];
    #pragma unroll
    for (int n = 0; n < 8; n++) sj[n] = s[jb + n * 16 + l16];

    // ---- 3) MFMA in two col-halves (register-pressure capped).
    f32x4 acc[2][8] = {};
    #pragma unroll
    for (int h = 0; h < 2; h++) {
        short8 b[4][4];
        #pragma unroll
        for (int n = 0; n < 4; n++)
            #pragma unroll
            for (int k = 0; k < 4; k++)
                b[n][k] = Fr[((tj * 8 + h * 4 + n) * 4 + k) * 64 + lane];
        #pragma unroll
        for (int k = 0; k < 4; k++)
            #pragma unroll
            for (int n = 0; n < 4; n++)
                #pragma unroll
                for (int rg = 0; rg < 2; rg++)
                    acc[rg][h * 4 + n] = __builtin_amdgcn_mfma_f32_16x16x32_bf16(
                        a[rg][k], b[n][k], acc[rg][h * 4 + n], 0, 0, 0);
        if (h == 0) __builtin_amdgcn_sched_barrier(0);  // don't hoist half-2 loads
    }

    // ---- 4) This wave's DMAs (oldest VMEM) certainly done; fence the
    // ds_reads from moving above (rule #18).
    asm volatile("s_waitcnt vmcnt(0)" ::: "memory");
    __builtin_amdgcn_sched_barrier(0);

    // ---- 5) Epilogue. C/D layout: col = l16 (+cg*16), row = quad*4 + reg.
    // f64 accumulation of identical f32 element values (safer than any f32
    // grouping; reference is f64).
    double lsum = 0.0;
    if (ti != tj) {
        #pragma unroll
        for (int rg = 0; rg < 2; rg++)
            #pragma unroll
            for (int n = 0; n < 8; n++)
                #pragma unroll
                for (int r = 0; r < 4; r++) {
                    const float B  = fmaf(si[rg][r], sj[n], -acc[rg][n][r]);
                    const float tv = T[rbase + rg * 16 + r][n * 16 + l16];
                    lsum += (double)fabsf(acosh_dist(B) - tv);
                }
    } else {
        #pragma unroll
        for (int rg = 0; rg < 2; rg++)
            #pragma unroll
            for (int n = 0; n < 8; n++)
                #pragma unroll
                for (int r = 0; r < 4; r++) {
                    const int i = ib0 + rbase + rg * 16 + r;
                    const int j = jb + n * 16 + l16;
                    if (j < i) {
                        const float B  = fmaf(si[rg][r], sj[n], -acc[rg][n][r]);
                        const float tv = T[rbase + rg * 16 + r][n * 16 + l16];
                        lsum += (double)fabsf(acosh_dist(B) - tv);
                    }
                }
    }

    #pragma unroll
    for (int off = 32; off > 0; off >>= 1)
        lsum += __shfl_down(lsum, off, 64);
    if (lane == 0) wpart[blockIdx.x * 4 + wave] = (float)lsum;
}

// Kernel 3: reduce 528x4 wave-partials in f64, scale, write scalar loss.
__global__ __launch_bounds__(256)
void final_reduce_kernel(const float* __restrict__ wpart,
                         float* __restrict__ loss) {
    __shared__ double wsum[4];
    const int tid  = threadIdx.x;
    const int wave = tid >> 6;
    const int lane = tid & 63;
    double acc = 0.0;
    for (int i = tid; i < NBLK * 4; i += 256) acc += (double)wpart[i];
    #pragma unroll
    for (int off = 32; off > 0; off >>= 1)
        acc += __shfl_down(acc, off, 64);
    if (lane == 0) wsum[wave] = acc;
    __syncthreads();
    if (tid == 0) {
        const double tot = ((wsum[0] + wsum[1]) + wsum[2]) + wsum[3];
        loss[0] = (float)(tot * (1.0 / ((double)N * (double)(N - 1))));
    }
}

extern "C" void kernel_launch(void* const* d_in, const int* in_sizes, int n_in,
                              void* d_out, int out_size, void* d_ws, size_t ws_size,
                              hipStream_t stream) {
    const float* O   = (const float*)d_in[0];   // [4096,128] fp32
    const float* tgt = (const float*)d_in[1];   // [4096,4096] fp32
    float* loss = (float*)d_out;                // scalar

    // ws layout: [0,1MB) frag-ordered bf16 O; then s[N]; then wave partials
    short8* Ofrag = (short8*)d_ws;
    float* s      = (float*)((char*)d_ws + (size_t)N * D * 2);
    float* wpart  = s + N;                      // NBLK*4 floats

    prep_kernel<<<NG, 256, 0, stream>>>(O, Ofrag, s);
    tile_loss_kernel<<<NBLK, 256, 0, stream>>>(Ofrag, s, tgt, wpart);
    final_reduce_kernel<<<1, 256, 0, stream>>>(wpart, loss);
}